// Round 6
// baseline (4148.976 us; speedup 1.0000x reference)
//
#include <hip/hip_runtime.h>
#include <cstdint>
#include <cstddef>

#define T_SEQ 1024
#define BATCH 64
#define DIM   256
#define HID   256
#define NG    (4*HID)   // 1024 gate columns, j = g*256 + r, g in {f,i,g~,o}

typedef _Float16 h2v __attribute__((ext_vector_type(2)));
union U16 { uint4 u; h2v h[4]; };

__device__ __forceinline__ float sigm_f(float x) {
    return 1.0f / (1.0f + __expf(-x));
}
__device__ __forceinline__ float tanh_f(float x) {
    x = fminf(fmaxf(x, -15.0f), 15.0f);   // avoid inf/inf
    float e = __expf(2.0f * x);
    return (e - 1.0f) / (e + 1.0f);
}

// ---------------- phase 0: repack weights, zero state -------------------------
// wx4[(k*256 + r)*4 + g] = W_g[r][k]                     (x part, fp32)
// wzh[((k>>3)*1024 + j)*8 + (k&7)] = fp16(W_g[r][256+k]) (h part, fp16 k-packs of 8)
// bias4[r*4+g] = b_g[r]
__global__ void pack_kernel(const float* __restrict__ Wf, const float* __restrict__ bf,
                            const float* __restrict__ Wi, const float* __restrict__ bi,
                            const float* __restrict__ Wg, const float* __restrict__ bg,
                            const float* __restrict__ Wo, const float* __restrict__ bo,
                            float* __restrict__ wx4, _Float16* __restrict__ wzh,
                            float* __restrict__ bias4,
                            float* __restrict__ hstate, float* __restrict__ cstate) {
    int k = blockIdx.x;          // 0..255
    int j = threadIdx.x;         // 0..1023
    int r = j & 255, g = j >> 8;
    const float* W  = (g == 0) ? Wf : (g == 1) ? Wi : (g == 2) ? Wg : Wo;
    const float* bb = (g == 0) ? bf : (g == 1) ? bi : (g == 2) ? bg : bo;
    wx4[((size_t)k * 256 + r) * 4 + g] = W[(size_t)r * 512 + k];
    wzh[(((size_t)(k >> 3)) * 1024 + j) * 8 + (k & 7)] = (_Float16)W[(size_t)r * 512 + 256 + k];
    if (k == 0) bias4[r * 4 + g] = bb[r];
    if (k < 64 && g == 0) hstate[k * 256 + r] = 0.0f;
    if (k < 64 && g == 1) cstate[k * 256 + r] = 0.0f;
}

// ---------------- phase 1: Xproj[row][j] = x_row . Wx_col_j + bias ------------
__global__ __launch_bounds__(256) void xproj_kernel(
        const float* __restrict__ X, const float* __restrict__ wx4,
        const float* __restrict__ bias4, float* __restrict__ xp) {
    __shared__ __align__(16) float xl[256 * 20];   // [k][row] padded
    int tid = threadIdx.x;
    int R0 = blockIdx.x * 16;
    #pragma unroll
    for (int i = 0; i < 16; ++i)
        xl[tid * 20 + i] = X[(size_t)(R0 + i) * DIM + tid];
    __syncthreads();

    float4 bv = ((const float4*)bias4)[tid];
    float acc[16][4];
    #pragma unroll
    for (int i = 0; i < 16; ++i) {
        acc[i][0] = bv.x; acc[i][1] = bv.y; acc[i][2] = bv.z; acc[i][3] = bv.w;
    }
    const float4* __restrict__ wp = (const float4*)wx4 + tid;
    #pragma unroll 2
    for (int k = 0; k < 256; ++k) {
        float4 w  = wp[k << 8];
        float4 xa = *(const float4*)&xl[k * 20 + 0];
        float4 xb = *(const float4*)&xl[k * 20 + 4];
        float4 xc = *(const float4*)&xl[k * 20 + 8];
        float4 xd = *(const float4*)&xl[k * 20 + 12];
        float xr[16] = {xa.x, xa.y, xa.z, xa.w, xb.x, xb.y, xb.z, xb.w,
                        xc.x, xc.y, xc.z, xc.w, xd.x, xd.y, xd.z, xd.w};
        #pragma unroll
        for (int i = 0; i < 16; ++i) {
            acc[i][0] = fmaf(xr[i], w.x, acc[i][0]);
            acc[i][1] = fmaf(xr[i], w.y, acc[i][1]);
            acc[i][2] = fmaf(xr[i], w.z, acc[i][2]);
            acc[i][3] = fmaf(xr[i], w.w, acc[i][3]);
        }
    }
    #pragma unroll
    for (int i = 0; i < 16; ++i)
        #pragma unroll
        for (int g = 0; g < 4; ++g)
            xp[(size_t)(R0 + i) * NG + g * HID + tid] = acc[i][g];
}

// ---------------- phase 2: sequential recurrence, 1 WG per batch element -----
// 256 threads (4 waves); thread t owns columns 4t..4t+3 (contiguous).
// Wave w handles gate w exactly (column j = 256w + 4*lane + q) -> wave-uniform
// activation. Weights: k8 in [0,8) -> 128 KB LDS slab; k8 in [8,32) -> 96 uint4
// per thread in registers (384 VGPRs). Zero per-step weight streaming.
__global__ __launch_bounds__(256, 1) void lstm_step_kernel(
        const float* __restrict__ xp, const _Float16* __restrict__ wzh,
        float* __restrict__ hstate, float* __restrict__ cstate,
        float* __restrict__ out, int t0, int Tc) {
    __shared__ __align__(16) _Float16 wl[8 * 1024 * 8];   // 128 KB: k8 = 0..7
    __shared__ __align__(16) _Float16 hl2[HID];           // fp16 h
    __shared__ __align__(16) float gl[NG];
    int t = threadIdx.x, b = blockIdx.x;

    // stage k8 = 0..7 into LDS (8192 uint4 over 256 threads = 32 each)
    {
        const uint4* src = (const uint4*)wzh;
        uint4* dst = (uint4*)wl;
        #pragma unroll
        for (int i = 0; i < 32; ++i)
            dst[i * 256 + t] = src[i * 256 + t];
    }
    // register slab: k8 = 8..31 for columns 4t..4t+3 (96 uint4 = 384 regs)
    uint4 wr0[24], wr1[24], wr2[24], wr3[24];
    {
        const uint4* src = (const uint4*)wzh;
        #pragma unroll
        for (int i = 0; i < 24; ++i) {
            wr0[i] = src[(size_t)(8 + i) * 1024 + 4 * t + 0];
            wr1[i] = src[(size_t)(8 + i) * 1024 + 4 * t + 1];
            wr2[i] = src[(size_t)(8 + i) * 1024 + 4 * t + 2];
            wr3[i] = src[(size_t)(8 + i) * 1024 + 4 * t + 3];
        }
    }
    float creg = cstate[b * HID + t];
    hl2[t] = (_Float16)hstate[b * HID + t];
    __syncthreads();

    bool is_tanh_wave = ((t >> 6) == 2);   // wave 2 = gate g~ -> tanh

    for (int tt = 0; tt < Tc; ++tt) {
        float4 av = *(const float4*)&xp[((size_t)tt * BATCH + b) * NG + 4 * t];
        float s0a = 0.f, s0b = 0.f, s1a = 0.f, s1b = 0.f;
        float s2a = 0.f, s2b = 0.f, s3a = 0.f, s3b = 0.f;
        // LDS-slab part: k8 = 0..7
        #pragma unroll
        for (int k8 = 0; k8 < 8; ++k8) {
            U16 h, w0, w1, w2, w3;
            h.u  = *(const uint4*)&hl2[k8 * 8];                        // broadcast
            w0.u = *(const uint4*)&wl[(size_t)(k8 * 1024 + 4 * t + 0) * 8];
            w1.u = *(const uint4*)&wl[(size_t)(k8 * 1024 + 4 * t + 1) * 8];
            w2.u = *(const uint4*)&wl[(size_t)(k8 * 1024 + 4 * t + 2) * 8];
            w3.u = *(const uint4*)&wl[(size_t)(k8 * 1024 + 4 * t + 3) * 8];
            s0a = __builtin_amdgcn_fdot2(w0.h[0], h.h[0], s0a, false);
            s0b = __builtin_amdgcn_fdot2(w0.h[1], h.h[1], s0b, false);
            s0a = __builtin_amdgcn_fdot2(w0.h[2], h.h[2], s0a, false);
            s0b = __builtin_amdgcn_fdot2(w0.h[3], h.h[3], s0b, false);
            s1a = __builtin_amdgcn_fdot2(w1.h[0], h.h[0], s1a, false);
            s1b = __builtin_amdgcn_fdot2(w1.h[1], h.h[1], s1b, false);
            s1a = __builtin_amdgcn_fdot2(w1.h[2], h.h[2], s1a, false);
            s1b = __builtin_amdgcn_fdot2(w1.h[3], h.h[3], s1b, false);
            s2a = __builtin_amdgcn_fdot2(w2.h[0], h.h[0], s2a, false);
            s2b = __builtin_amdgcn_fdot2(w2.h[1], h.h[1], s2b, false);
            s2a = __builtin_amdgcn_fdot2(w2.h[2], h.h[2], s2a, false);
            s2b = __builtin_amdgcn_fdot2(w2.h[3], h.h[3], s2b, false);
            s3a = __builtin_amdgcn_fdot2(w3.h[0], h.h[0], s3a, false);
            s3b = __builtin_amdgcn_fdot2(w3.h[1], h.h[1], s3b, false);
            s3a = __builtin_amdgcn_fdot2(w3.h[2], h.h[2], s3a, false);
            s3b = __builtin_amdgcn_fdot2(w3.h[3], h.h[3], s3b, false);
        }
        // register-slab part: k8 = 8..31
        #pragma unroll
        for (int i = 0; i < 24; ++i) {
            U16 h, w0, w1, w2, w3;
            h.u  = *(const uint4*)&hl2[(8 + i) * 8];                   // broadcast
            w0.u = wr0[i]; w1.u = wr1[i]; w2.u = wr2[i]; w3.u = wr3[i];
            s0a = __builtin_amdgcn_fdot2(w0.h[0], h.h[0], s0a, false);
            s0b = __builtin_amdgcn_fdot2(w0.h[1], h.h[1], s0b, false);
            s0a = __builtin_amdgcn_fdot2(w0.h[2], h.h[2], s0a, false);
            s0b = __builtin_amdgcn_fdot2(w0.h[3], h.h[3], s0b, false);
            s1a = __builtin_amdgcn_fdot2(w1.h[0], h.h[0], s1a, false);
            s1b = __builtin_amdgcn_fdot2(w1.h[1], h.h[1], s1b, false);
            s1a = __builtin_amdgcn_fdot2(w1.h[2], h.h[2], s1a, false);
            s1b = __builtin_amdgcn_fdot2(w1.h[3], h.h[3], s1b, false);
            s2a = __builtin_amdgcn_fdot2(w2.h[0], h.h[0], s2a, false);
            s2b = __builtin_amdgcn_fdot2(w2.h[1], h.h[1], s2b, false);
            s2a = __builtin_amdgcn_fdot2(w2.h[2], h.h[2], s2a, false);
            s2b = __builtin_amdgcn_fdot2(w2.h[3], h.h[3], s2b, false);
            s3a = __builtin_amdgcn_fdot2(w3.h[0], h.h[0], s3a, false);
            s3b = __builtin_amdgcn_fdot2(w3.h[1], h.h[1], s3b, false);
            s3a = __builtin_amdgcn_fdot2(w3.h[2], h.h[2], s3a, false);
            s3b = __builtin_amdgcn_fdot2(w3.h[3], h.h[3], s3b, false);
        }
        float a0 = av.x + s0a + s0b;
        float a1 = av.y + s1a + s1b;
        float a2 = av.z + s2a + s2b;
        float a3 = av.w + s3a + s3b;
        float4 gv;
        if (is_tanh_wave) {
            gv.x = tanh_f(a0); gv.y = tanh_f(a1); gv.z = tanh_f(a2); gv.w = tanh_f(a3);
        } else {
            gv.x = sigm_f(a0); gv.y = sigm_f(a1); gv.z = sigm_f(a2); gv.w = sigm_f(a3);
        }
        *(float4*)&gl[4 * t] = gv;
        __syncthreads();
        // elementwise update: thread t = hidden unit t
        {
            float f  = gl[t];
            float ii = gl[256 + t];
            float gg = gl[512 + t];
            float o  = gl[768 + t];
            float c  = fmaf(f, creg, ii * gg);
            creg = c;
            float h = o * tanh_f(c);
            hl2[t] = (_Float16)h;
            out[((size_t)(t0 + tt) * BATCH + b) * HID + t] = h;
        }
        __syncthreads();
    }
    hstate[b * HID + t] = (float)hl2[t];
    cstate[b * HID + t] = creg;
}

// ---------------- tail: final hx, cx ------------------------------------------
__global__ void tail_kernel(const float* __restrict__ hstate,
                            const float* __restrict__ cstate, float* __restrict__ out) {
    int b = blockIdx.x, r = threadIdx.x;
    size_t base = (size_t)T_SEQ * BATCH * HID;
    out[base + b * HID + r] = hstate[b * HID + r];
    out[base + (size_t)BATCH * HID + b * HID + r] = cstate[b * HID + r];
}

extern "C" void kernel_launch(void* const* d_in, const int* in_sizes, int n_in,
                              void* d_out, int out_size, void* d_ws, size_t ws_size,
                              hipStream_t stream) {
    (void)in_sizes; (void)n_in; (void)out_size;
    const float* X  = (const float*)d_in[0];
    const float* Wf = (const float*)d_in[1];
    const float* bf = (const float*)d_in[2];
    const float* Wi = (const float*)d_in[3];
    const float* bi = (const float*)d_in[4];
    const float* Wg = (const float*)d_in[5];
    const float* bg = (const float*)d_in[6];
    const float* Wo = (const float*)d_in[7];
    const float* bo = (const float*)d_in[8];
    float* out = (float*)d_out;
    char*  ws  = (char*)d_ws;

    const size_t MB = 1 << 20, KB = 1 << 10;
    float*    wx4    = (float*)(ws);                          // 1 MB
    _Float16* wzh    = (_Float16*)(ws + MB);                  // 512 KB
    float*    bias4  = (float*)(ws + MB + 512 * KB);          // 4 KB
    float*    hstate = (float*)(ws + MB + 576 * KB);          // 64 KB
    float*    cstate = (float*)(ws + MB + 640 * KB);          // 64 KB
    float*    xproj  = (float*)(ws + 2 * MB);

    size_t fixed = 2 * MB;
    int Tc = 1024;
    while (Tc > 16 && fixed + (size_t)Tc * BATCH * NG * 4 > ws_size) Tc >>= 1;

    pack_kernel<<<256, 1024, 0, stream>>>(Wf, bf, Wi, bi, Wg, bg, Wo, bo,
                                          wx4, wzh, bias4, hstate, cstate);
    for (int t0 = 0; t0 < T_SEQ; t0 += Tc) {
        xproj_kernel<<<Tc * BATCH / 16, 256, 0, stream>>>(
            X + (size_t)t0 * BATCH * DIM, wx4, bias4, xproj);
        lstm_step_kernel<<<BATCH, 256, 0, stream>>>(
            xproj, wzh, hstate, cstate, out, t0, Tc);
    }
    tail_kernel<<<BATCH, HID, 0, stream>>>(hstate, cstate, out);
}

// Round 7
// 3851.858 us; speedup vs baseline: 1.0771x; 1.0771x over previous
//
#include <hip/hip_runtime.h>
#include <cstdint>
#include <cstddef>

#define T_SEQ 1024
#define BATCH 64
#define DIM   256
#define HID   256
#define NG    (4*HID)   // 1024 gate columns, j = g*256 + r, g in {f,i,g~,o}

typedef _Float16 h2v __attribute__((ext_vector_type(2)));
union U16 { uint4 u; h2v h[4]; };

__device__ __forceinline__ float sigm_f(float x) {
    return 1.0f / (1.0f + __expf(-x));
}
__device__ __forceinline__ float tanh_f(float x) {
    x = fminf(fmaxf(x, -15.0f), 15.0f);   // avoid inf/inf
    float e = __expf(2.0f * x);
    return (e - 1.0f) / (e + 1.0f);
}

// ---------------- phase 0: repack weights, zero state -------------------------
// wx4[(k*256 + r)*4 + g] = W_g[r][k]                     (x part, fp32)
// wzh[((k>>3)*1024 + j)*8 + (k&7)] = fp16(W_g[r][256+k]) (h part, fp16 k-packs of 8)
// bias4[r*4+g] = b_g[r]
__global__ void pack_kernel(const float* __restrict__ Wf, const float* __restrict__ bf,
                            const float* __restrict__ Wi, const float* __restrict__ bi,
                            const float* __restrict__ Wg, const float* __restrict__ bg,
                            const float* __restrict__ Wo, const float* __restrict__ bo,
                            float* __restrict__ wx4, _Float16* __restrict__ wzh,
                            float* __restrict__ bias4,
                            float* __restrict__ hstate, float* __restrict__ cstate) {
    int k = blockIdx.x;          // 0..255
    int j = threadIdx.x;         // 0..1023
    int r = j & 255, g = j >> 8;
    const float* W  = (g == 0) ? Wf : (g == 1) ? Wi : (g == 2) ? Wg : Wo;
    const float* bb = (g == 0) ? bf : (g == 1) ? bi : (g == 2) ? bg : bo;
    wx4[((size_t)k * 256 + r) * 4 + g] = W[(size_t)r * 512 + k];
    wzh[(((size_t)(k >> 3)) * 1024 + j) * 8 + (k & 7)] = (_Float16)W[(size_t)r * 512 + 256 + k];
    if (k == 0) bias4[r * 4 + g] = bb[r];
    if (k < 64 && g == 0) hstate[k * 256 + r] = 0.0f;
    if (k < 64 && g == 1) cstate[k * 256 + r] = 0.0f;
}

// ---------------- phase 1: Xproj[row][4r+g] = x_row . Wx_col + bias -----------
// NOTE: gate-interleaved output layout (r*4+g) so lstm loads one float4/thread.
__global__ __launch_bounds__(256) void xproj_kernel(
        const float* __restrict__ X, const float* __restrict__ wx4,
        const float* __restrict__ bias4, float* __restrict__ xp) {
    __shared__ __align__(16) float xl[256 * 20];   // [k][row] padded
    int tid = threadIdx.x;
    int R0 = blockIdx.x * 16;
    #pragma unroll
    for (int i = 0; i < 16; ++i)
        xl[tid * 20 + i] = X[(size_t)(R0 + i) * DIM + tid];
    __syncthreads();

    float4 bv = ((const float4*)bias4)[tid];
    float acc[16][4];
    #pragma unroll
    for (int i = 0; i < 16; ++i) {
        acc[i][0] = bv.x; acc[i][1] = bv.y; acc[i][2] = bv.z; acc[i][3] = bv.w;
    }
    const float4* __restrict__ wp = (const float4*)wx4 + tid;
    #pragma unroll 2
    for (int k = 0; k < 256; ++k) {
        float4 w  = wp[k << 8];
        float4 xa = *(const float4*)&xl[k * 20 + 0];
        float4 xb = *(const float4*)&xl[k * 20 + 4];
        float4 xc = *(const float4*)&xl[k * 20 + 8];
        float4 xd = *(const float4*)&xl[k * 20 + 12];
        float xr[16] = {xa.x, xa.y, xa.z, xa.w, xb.x, xb.y, xb.z, xb.w,
                        xc.x, xc.y, xc.z, xc.w, xd.x, xd.y, xd.z, xd.w};
        #pragma unroll
        for (int i = 0; i < 16; ++i) {
            acc[i][0] = fmaf(xr[i], w.x, acc[i][0]);
            acc[i][1] = fmaf(xr[i], w.y, acc[i][1]);
            acc[i][2] = fmaf(xr[i], w.z, acc[i][2]);
            acc[i][3] = fmaf(xr[i], w.w, acc[i][3]);
        }
    }
    #pragma unroll
    for (int i = 0; i < 16; ++i) {
        float4 v; v.x = acc[i][0]; v.y = acc[i][1]; v.z = acc[i][2]; v.w = acc[i][3];
        *(float4*)&xp[(size_t)(R0 + i) * NG + 4 * tid] = v;   // interleaved
    }
}

// ---------------- phase 2: sequential recurrence, 1 WG per batch element -----
// 256 threads (4 waves); thread t owns columns {t, 256+t, 512+t, 768+t} =
// (f_t, i_t, g~_t, o_t) -> elementwise update is thread-local (no gate
// exchange, no divergence: every thread does 3 sigm + 2 tanh).
// LDS lane stride = 16 B (conflict-free, measured r5). h double-buffered by
// parity -> ONE barrier per step. Weights: k8 0..7 in 128 KB LDS slab,
// k8 8..31 in 96 uint4/thread of registers. Zero per-step weight streaming.
__global__ __launch_bounds__(256, 1) void lstm_step_kernel(
        const float* __restrict__ xp, const _Float16* __restrict__ wzh,
        float* __restrict__ hstate, float* __restrict__ cstate,
        float* __restrict__ out, int t0, int Tc) {
    __shared__ __align__(16) _Float16 wl[8 * 1024 * 8];   // 128 KB: k8 = 0..7
    __shared__ __align__(16) _Float16 hbuf[2][HID];       // parity double buffer
    int t = threadIdx.x, b = blockIdx.x;

    // stage k8 = 0..7 into LDS (8192 uint4 over 256 threads = 32 each)
    {
        const uint4* src = (const uint4*)wzh;
        uint4* dst = (uint4*)wl;
        #pragma unroll
        for (int i = 0; i < 32; ++i)
            dst[i * 256 + t] = src[i * 256 + t];
    }
    // register slab: k8 = 8..31, columns q*256+t (96 uint4 = 384 regs)
    uint4 wr0[24], wr1[24], wr2[24], wr3[24];
    {
        const uint4* src = (const uint4*)wzh;
        #pragma unroll
        for (int i = 0; i < 24; ++i) {
            wr0[i] = src[(size_t)(8 + i) * 1024 +   0 + t];
            wr1[i] = src[(size_t)(8 + i) * 1024 + 256 + t];
            wr2[i] = src[(size_t)(8 + i) * 1024 + 512 + t];
            wr3[i] = src[(size_t)(8 + i) * 1024 + 768 + t];
        }
    }
    float creg = cstate[b * HID + t];
    float hreg = hstate[b * HID + t];
    hbuf[0][t] = (_Float16)hreg;
    __syncthreads();

    int p = 0;
    for (int tt = 0; tt < Tc; ++tt) {
        const _Float16* hl = hbuf[p];
        float4 av = *(const float4*)&xp[((size_t)tt * BATCH + b) * NG + 4 * t];
        float s0a = 0.f, s0b = 0.f, s1a = 0.f, s1b = 0.f;
        float s2a = 0.f, s2b = 0.f, s3a = 0.f, s3b = 0.f;
        // LDS-slab part: k8 = 0..7  (one h broadcast serves 4 columns)
        #pragma unroll
        for (int k8 = 0; k8 < 8; ++k8) {
            U16 h, w0, w1, w2, w3;
            h.u  = *(const uint4*)&hl[k8 * 8];                       // broadcast
            w0.u = *(const uint4*)&wl[(size_t)(k8 * 1024 +   0 + t) * 8];
            w1.u = *(const uint4*)&wl[(size_t)(k8 * 1024 + 256 + t) * 8];
            w2.u = *(const uint4*)&wl[(size_t)(k8 * 1024 + 512 + t) * 8];
            w3.u = *(const uint4*)&wl[(size_t)(k8 * 1024 + 768 + t) * 8];
            s0a = __builtin_amdgcn_fdot2(w0.h[0], h.h[0], s0a, false);
            s0b = __builtin_amdgcn_fdot2(w0.h[1], h.h[1], s0b, false);
            s0a = __builtin_amdgcn_fdot2(w0.h[2], h.h[2], s0a, false);
            s0b = __builtin_amdgcn_fdot2(w0.h[3], h.h[3], s0b, false);
            s1a = __builtin_amdgcn_fdot2(w1.h[0], h.h[0], s1a, false);
            s1b = __builtin_amdgcn_fdot2(w1.h[1], h.h[1], s1b, false);
            s1a = __builtin_amdgcn_fdot2(w1.h[2], h.h[2], s1a, false);
            s1b = __builtin_amdgcn_fdot2(w1.h[3], h.h[3], s1b, false);
            s2a = __builtin_amdgcn_fdot2(w2.h[0], h.h[0], s2a, false);
            s2b = __builtin_amdgcn_fdot2(w2.h[1], h.h[1], s2b, false);
            s2a = __builtin_amdgcn_fdot2(w2.h[2], h.h[2], s2a, false);
            s2b = __builtin_amdgcn_fdot2(w2.h[3], h.h[3], s2b, false);
            s3a = __builtin_amdgcn_fdot2(w3.h[0], h.h[0], s3a, false);
            s3b = __builtin_amdgcn_fdot2(w3.h[1], h.h[1], s3b, false);
            s3a = __builtin_amdgcn_fdot2(w3.h[2], h.h[2], s3a, false);
            s3b = __builtin_amdgcn_fdot2(w3.h[3], h.h[3], s3b, false);
        }
        // register-slab part: k8 = 8..31
        #pragma unroll
        for (int i = 0; i < 24; ++i) {
            U16 h, w0, w1, w2, w3;
            h.u  = *(const uint4*)&hl[(8 + i) * 8];                  // broadcast
            w0.u = wr0[i]; w1.u = wr1[i]; w2.u = wr2[i]; w3.u = wr3[i];
            s0a = __builtin_amdgcn_fdot2(w0.h[0], h.h[0], s0a, false);
            s0b = __builtin_amdgcn_fdot2(w0.h[1], h.h[1], s0b, false);
            s0a = __builtin_amdgcn_fdot2(w0.h[2], h.h[2], s0a, false);
            s0b = __builtin_amdgcn_fdot2(w0.h[3], h.h[3], s0b, false);
            s1a = __builtin_amdgcn_fdot2(w1.h[0], h.h[0], s1a, false);
            s1b = __builtin_amdgcn_fdot2(w1.h[1], h.h[1], s1b, false);
            s1a = __builtin_amdgcn_fdot2(w1.h[2], h.h[2], s1a, false);
            s1b = __builtin_amdgcn_fdot2(w1.h[3], h.h[3], s1b, false);
            s2a = __builtin_amdgcn_fdot2(w2.h[0], h.h[0], s2a, false);
            s2b = __builtin_amdgcn_fdot2(w2.h[1], h.h[1], s2b, false);
            s2a = __builtin_amdgcn_fdot2(w2.h[2], h.h[2], s2a, false);
            s2b = __builtin_amdgcn_fdot2(w2.h[3], h.h[3], s2b, false);
            s3a = __builtin_amdgcn_fdot2(w3.h[0], h.h[0], s3a, false);
            s3b = __builtin_amdgcn_fdot2(w3.h[1], h.h[1], s3b, false);
            s3a = __builtin_amdgcn_fdot2(w3.h[2], h.h[2], s3a, false);
            s3b = __builtin_amdgcn_fdot2(w3.h[3], h.h[3], s3b, false);
        }
        float f  = sigm_f(av.x + s0a + s0b);
        float ii = sigm_f(av.y + s1a + s1b);
        float gg = tanh_f(av.z + s2a + s2b);
        float o  = sigm_f(av.w + s3a + s3b);
        float c  = fmaf(f, creg, ii * gg);
        creg = c;
        float h = o * tanh_f(c);
        hreg = h;
        hbuf[p ^ 1][t] = (_Float16)h;     // write other buffer: no read race
        out[((size_t)(t0 + tt) * BATCH + b) * HID + t] = h;
        p ^= 1;
        __syncthreads();                  // single barrier per step
    }
    hstate[b * HID + t] = hreg;
    cstate[b * HID + t] = creg;
}

// ---------------- tail: final hx, cx ------------------------------------------
__global__ void tail_kernel(const float* __restrict__ hstate,
                            const float* __restrict__ cstate, float* __restrict__ out) {
    int b = blockIdx.x, r = threadIdx.x;
    size_t base = (size_t)T_SEQ * BATCH * HID;
    out[base + b * HID + r] = hstate[b * HID + r];
    out[base + (size_t)BATCH * HID + b * HID + r] = cstate[b * HID + r];
}

extern "C" void kernel_launch(void* const* d_in, const int* in_sizes, int n_in,
                              void* d_out, int out_size, void* d_ws, size_t ws_size,
                              hipStream_t stream) {
    (void)in_sizes; (void)n_in; (void)out_size;
    const float* X  = (const float*)d_in[0];
    const float* Wf = (const float*)d_in[1];
    const float* bf = (const float*)d_in[2];
    const float* Wi = (const float*)d_in[3];
    const float* bi = (const float*)d_in[4];
    const float* Wg = (const float*)d_in[5];
    const float* bg = (const float*)d_in[6];
    const float* Wo = (const float*)d_in[7];
    const float* bo = (const float*)d_in[8];
    float* out = (float*)d_out;
    char*  ws  = (char*)d_ws;

    const size_t MB = 1 << 20, KB = 1 << 10;
    float*    wx4    = (float*)(ws);                          // 1 MB
    _Float16* wzh    = (_Float16*)(ws + MB);                  // 512 KB
    float*    bias4  = (float*)(ws + MB + 512 * KB);          // 4 KB
    float*    hstate = (float*)(ws + MB + 576 * KB);          // 64 KB
    float*    cstate = (float*)(ws + MB + 640 * KB);          // 64 KB
    float*    xproj  = (float*)(ws + 2 * MB);

    size_t fixed = 2 * MB;
    int Tc = 1024;
    while (Tc > 16 && fixed + (size_t)Tc * BATCH * NG * 4 > ws_size) Tc >>= 1;

    pack_kernel<<<256, 1024, 0, stream>>>(Wf, bf, Wi, bi, Wg, bg, Wo, bo,
                                          wx4, wzh, bias4, hstate, cstate);
    for (int t0 = 0; t0 < T_SEQ; t0 += Tc) {
        xproj_kernel<<<Tc * BATCH / 16, 256, 0, stream>>>(
            X + (size_t)t0 * BATCH * DIM, wx4, bias4, xproj);
        lstm_step_kernel<<<BATCH, 256, 0, stream>>>(
            xproj, wzh, hstate, cstate, out, t0, Tc);
    }
    tail_kernel<<<BATCH, HID, 0, stream>>>(hstate, cstate, out);
}